// Round 16
// baseline (122.193 us; speedup 1.0000x reference)
//
#include <hip/hip_runtime.h>
#include <limits.h>
#include <stdint.h>

#define ALPHA 0.2f
#define HALFA 0.1f
static constexpr int N = 8192;
static constexpr int D = 128;
static constexpr int C = 512;
static constexpr int BT = 128;          // block tile (i and j)
static constexpr int KC = 32;           // k-chunk in fp16 elems (R4-proven)
static constexpr int SL = 40;           // LDS row stride in fp16 (32 + 8 pad, R4-proven)
static constexpr int NB = N / BT;       // 64
static constexpr int NTRI = NB * (NB + 1) / 2;   // 2080 triangle blocks
static constexpr int MAXG = 64;         // e-list capacity (Poisson(16); >8 sigma)
static constexpr int ABIAS = 0x40000000; // anchor encode: raw = ABIAS - idx (raw>0 <=> present)

using half8   = __attribute__((ext_vector_type(8))) _Float16;
using floatx16 = __attribute__((ext_vector_type(16))) float;

__device__ __forceinline__ floatx16 zerov() { floatx16 v = {0.f}; return v; }

__device__ __forceinline__ half8 cvt8(float4 v0, float4 v1) {
    half8 h;
    h[0] = (_Float16)v0.x; h[1] = (_Float16)v0.y; h[2] = (_Float16)v0.z; h[3] = (_Float16)v0.w;
    h[4] = (_Float16)v1.x; h[5] = (_Float16)v1.y; h[6] = (_Float16)v1.z; h[7] = (_Float16)v1.w;
    return h;
}

// ---------------- front: anchor-Gram from raw inputs; sq/xh folded into staging ----------------

__launch_bounds__(256)
__global__ void k_front(const float* __restrict__ x, const int* __restrict__ labels,
                        _Float16* __restrict__ xh, float* __restrict__ sqg,
                        int* __restrict__ anchorg, float* __restrict__ T,
                        float* __restrict__ ap, float* __restrict__ out) {
    __shared__ __align__(16) _Float16 As[BT * SL];   // anchor rows c0..
    __shared__ __align__(16) _Float16 Bs[BT * SL];   // rows j0..
    __shared__ float sSqA[BT];
    __shared__ float sSqJ[BT];
    __shared__ int sLabJ[BT];
    __shared__ int sA[BT];         // anchor idx (INT_MAX = absent)

    const int cb = blockIdx.x, jb = blockIdx.y;
    const int c0 = cb * BT;
    const int j0 = jb * BT;
    const int tid = threadIdx.x;
    const int lane = tid & 63, w = tid >> 6;
    const int wr = w >> 1, wc = w & 1;
    const int m = lane & 31, q = lane >> 5;

    if (tid < BT) { sA[tid] = INT_MAX; sSqA[tid] = 0.f; sSqJ[tid] = 0.f; }
    else sLabJ[tid - BT] = labels[j0 + tid - BT];
    __syncthreads();

    // scan labels -> anchors for c-range (LDS atomicMin)
    const int4* lab4 = (const int4*)labels;
    for (int t = tid; t < N / 4; t += 256) {
        int4 lv = lab4[t];
        int base = t * 4;
#pragma unroll
        for (int k = 0; k < 4; ++k) {
            int l = (k == 0) ? lv.x : (k == 1) ? lv.y : (k == 2) ? lv.z : lv.w;
            int li = l - c0;
            if ((unsigned)li < (unsigned)BT) atomicMin(&sA[li], base + k);
        }
    }
    if (blockIdx.x == 0 && blockIdx.y == 0 && tid == 0) out[0] = 0.f;
    __syncthreads();

    if (jb == 0 && tid < BT)
        anchorg[c0 + tid] = (sA[tid] == INT_MAX) ? -1 : (ABIAS - sA[tid]);

    floatx16 acc[2][2];
    acc[0][0] = zerov(); acc[0][1] = zerov(); acc[1][0] = zerov(); acc[1][1] = zerov();

    const _Float16* Abase = &As[(wr * 64 + m) * SL + q * 8];
    const _Float16* Bbase = &Bs[(wc * 64 + m) * SL + q * 8];

    for (int kc = 0; kc < D; kc += KC) {
        __syncthreads();
#pragma unroll
        for (int it = 0; it < 2; ++it) {
            int f = tid + it * 256;
            int row = f >> 2, g = f & 3;
            size_t go = (size_t)kc + g * 8;
            int ar = sA[row];
            bool absent = (ar == INT_MAX);
            if (absent) ar = 0;                      // dummy, never read downstream
            // A tile (anchor rows): fp32 load + cvt + sq accumulate
            float4 a0 = *(const float4*)(x + (size_t)ar * D + go);
            float4 a1 = *(const float4*)(x + (size_t)ar * D + go + 4);
            *(half8*)(&As[row * SL + g * 8]) = cvt8(a0, a1);
            if (!absent) {
                float ssA = a0.x*a0.x + a0.y*a0.y + a0.z*a0.z + a0.w*a0.w
                          + a1.x*a1.x + a1.y*a1.y + a1.z*a1.z + a1.w*a1.w;
                atomicAdd(&sSqA[row], ssA);
            }
            // B tile (j rows): fp32 load + cvt + sq accumulate + xh write (cb==0)
            float4 b0 = *(const float4*)(x + (size_t)(j0 + row) * D + go);
            float4 b1 = *(const float4*)(x + (size_t)(j0 + row) * D + go + 4);
            half8 hb = cvt8(b0, b1);
            *(half8*)(&Bs[row * SL + g * 8]) = hb;
            float ssB = b0.x*b0.x + b0.y*b0.y + b0.z*b0.z + b0.w*b0.w
                      + b1.x*b1.x + b1.y*b1.y + b1.z*b1.z + b1.w*b1.w;
            atomicAdd(&sSqJ[row], ssB);
            if (cb == 0) *(half8*)(xh + (size_t)(j0 + row) * D + go) = hb;
        }
        __syncthreads();
#pragma unroll
        for (int ks = 0; ks < KC; ks += 16) {
            half8 a0 = *(const half8*)(Abase + ks);
            half8 a1 = *(const half8*)(Abase + 32 * SL + ks);
            half8 b0 = *(const half8*)(Bbase + ks);
            half8 b1 = *(const half8*)(Bbase + 32 * SL + ks);
            acc[0][0] = __builtin_amdgcn_mfma_f32_32x32x16_f16(a0, b0, acc[0][0], 0, 0, 0);
            acc[0][1] = __builtin_amdgcn_mfma_f32_32x32x16_f16(a0, b1, acc[0][1], 0, 0, 0);
            acc[1][0] = __builtin_amdgcn_mfma_f32_32x32x16_f16(a1, b0, acc[1][0], 0, 0, 0);
            acc[1][1] = __builtin_amdgcn_mfma_f32_32x32x16_f16(a1, b1, acc[1][1], 0, 0, 0);
        }
    }

    // sq accumulation complete (last staging preceded the final barrier)
    if (cb == 0 && tid >= BT) sqg[j0 + tid - BT] = sSqJ[tid - BT];

    float sqj[2]; int labj[2];
#pragma unroll
    for (int tn = 0; tn < 2; ++tn) {
        int col = wc * 64 + tn * 32 + m;
        sqj[tn] = sSqJ[col];
        labj[tn] = sLabJ[col];
    }

#pragma unroll
    for (int tm = 0; tm < 2; ++tm) {
        int rbase = wr * 64 + tm * 32 + 4 * q;
#pragma unroll
        for (int rr = 0; rr < 16; ++rr) {
            int row = rbase + (rr & 3) + 8 * (rr >> 2);
            int c = c0 + row;
            float sqa = sSqA[row];
#pragma unroll
            for (int tn = 0; tn < 2; ++tn) {
                int col = wc * 64 + tn * 32 + m;
                float Dv = fmaf(-2.f, acc[tm][tn][rr], sqa + sqj[tn]);
                T[(size_t)c * N + j0 + col] = Dv;
                if (labj[tn] == c) ap[j0 + col] = Dv;
            }
        }
    }
}

// ---------------- mega: per-label term1 blocks + term2 triangle blocks (R15-proven) ----------

__launch_bounds__(256)
__global__ void k_mega(const _Float16* __restrict__ xh, const int* __restrict__ labels,
                       const int* __restrict__ anchor, const float* __restrict__ sq,
                       const float* __restrict__ ap, const float* __restrict__ T,
                       float* __restrict__ out) {
    __shared__ __align__(16) _Float16 As[BT * SL];
    __shared__ __align__(16) _Float16 Bs[BT * SL];
    __shared__ float4 rowE[BT];    // (e2i, labi bits, sq_i, -)
    __shared__ float4 colE[BT];    // (e2j, labj bits, sq_j, -)
    __shared__ float wsum[4];

    const int tid = threadIdx.x;
    const int lane = tid & 63, w = tid >> 6;
    float local = 0.f;

    if ((int)blockIdx.x < C) {
        // ---- term1, label c: gather e-list by scanning labels, then stream T[c][:] once ----
        const int c = blockIdx.x;
        __shared__ float sge[MAXG];
        __shared__ int sglen;
        int raw = anchor[c];
        if (raw > 0) {
            int a = ABIAS - raw;
            if (tid == 0) sglen = 0;
            __syncthreads();
            for (int t = tid; t < N; t += 256) {
                if (labels[t] == c && t != a) {
                    int slot = atomicAdd(&sglen, 1);
                    if (slot < MAXG) sge[slot] = ap[t] + HALFA;
                }
            }
            __syncthreads();
            int glen = sglen; if (glen > MAXG) glen = MAXG;
            if (glen > 0) {
                const float4* trow = (const float4*)(T + (size_t)c * N);
                const int4* lrow = (const int4*)labels;
#pragma unroll 2
                for (int ch = 0; ch < 8; ++ch) {
                    float4 tv = trow[ch * 256 + tid];
                    int4 lv = lrow[ch * 256 + tid];
                    for (int g = 0; g < glen; ++g) {
                        float e = sge[g];
                        float u;
                        u = e - tv.x; if (lv.x != c && __builtin_fabsf(u) < HALFA) local += u + HALFA;
                        u = e - tv.y; if (lv.y != c && __builtin_fabsf(u) < HALFA) local += u + HALFA;
                        u = e - tv.z; if (lv.z != c && __builtin_fabsf(u) < HALFA) local += u + HALFA;
                        u = e - tv.w; if (lv.w != c && __builtin_fabsf(u) < HALFA) local += u + HALFA;
                    }
                }
            }
        }
    } else {
        // ---- term2: symmetric Gram triangle, register-only epilogue ----
        int rem = blockIdx.x - C, br = 0;
        while (rem >= NB - br) { rem -= NB - br; ++br; }
        const int bc = br + rem;
        const int i0 = br * BT;
        const int j0 = bc * BT;
        const bool diag = (br == bc);
        const int wr = w >> 1, wc = w & 1;
        const int m = lane & 31, q = lane >> 5;

        if (tid < BT) {
            int i = i0 + tid;
            int li = labels[i];
            int a = ABIAS - anchor[li];
            float sqi = sq[i];
            float e2 = (i == a) ? -1e30f : ap[i] + HALFA - sqi;
            rowE[tid] = make_float4(e2, __int_as_float(li), sqi, 0.f);
        } else {
            int t = tid - BT;
            int j = j0 + t;
            int lj = labels[j];
            int a = ABIAS - anchor[lj];
            float sqj = sq[j];
            float e2 = (j == a) ? -1e30f : ap[j] + HALFA - sqj;
            colE[t] = make_float4(e2, __int_as_float(lj), sqj, 0.f);
        }

        floatx16 acc[2][2];
        acc[0][0] = zerov(); acc[0][1] = zerov(); acc[1][0] = zerov(); acc[1][1] = zerov();

        const _Float16* Abase = &As[(wr * 64 + m) * SL + q * 8];
        const _Float16* Bbase = &Bs[(wc * 64 + m) * SL + q * 8];

        for (int kc = 0; kc < D; kc += KC) {
            __syncthreads();
#pragma unroll
            for (int it = 0; it < 2; ++it) {
                int f = tid + it * 256;
                int row = f >> 2, g = f & 3;
                size_t go = (size_t)kc + g * 8;
                half8 v = *(const half8*)(xh + (size_t)(i0 + row) * D + go);
                *(half8*)(&As[row * SL + g * 8]) = v;
                half8 u = *(const half8*)(xh + (size_t)(j0 + row) * D + go);
                *(half8*)(&Bs[row * SL + g * 8]) = u;
            }
            __syncthreads();
#pragma unroll
            for (int ks = 0; ks < KC; ks += 16) {
                half8 a0 = *(const half8*)(Abase + ks);
                half8 a1 = *(const half8*)(Abase + 32 * SL + ks);
                half8 b0 = *(const half8*)(Bbase + ks);
                half8 b1 = *(const half8*)(Bbase + 32 * SL + ks);
                acc[0][0] = __builtin_amdgcn_mfma_f32_32x32x16_f16(a0, b0, acc[0][0], 0, 0, 0);
                acc[0][1] = __builtin_amdgcn_mfma_f32_32x32x16_f16(a0, b1, acc[0][1], 0, 0, 0);
                acc[1][0] = __builtin_amdgcn_mfma_f32_32x32x16_f16(a1, b0, acc[1][0], 0, 0, 0);
                acc[1][1] = __builtin_amdgcn_mfma_f32_32x32x16_f16(a1, b1, acc[1][1], 0, 0, 0);
            }
        }

        float sqj[2], e2j[2]; int labj[2];
#pragma unroll
        for (int tn = 0; tn < 2; ++tn) {
            float4 cj = colE[wc * 64 + tn * 32 + m];
            e2j[tn] = cj.x; labj[tn] = __float_as_int(cj.y); sqj[tn] = cj.z;
        }

        // ori1 (i pos): u2 = 2*dot + e2i - sq_j ; ori2 (j pos): u2b = 2*dot + e2j - sq_i
#pragma unroll
        for (int tm = 0; tm < 2; ++tm) {
            int rbase = wr * 64 + tm * 32 + 4 * q;
#pragma unroll
            for (int rr = 0; rr < 16; ++rr) {
                int row = rbase + (rr & 3) + 8 * (rr >> 2);
                float4 re = rowE[row];
                float e2i = re.x, sqi = re.z;
                int labi = __float_as_int(re.y);
#pragma unroll
                for (int tn = 0; tn < 2; ++tn) {
                    if (labi != labj[tn]) {
                        float dot = acc[tm][tn][rr];
                        float u2 = fmaf(2.f, dot, e2i - sqj[tn]);
                        if (__builtin_fabsf(u2) < HALFA) local += u2 + HALFA;
                        if (!diag) {
                            float u2b = fmaf(2.f, dot, e2j[tn] - sqi);
                            if (__builtin_fabsf(u2b) < HALFA) local += u2b + HALFA;
                        }
                    }
                }
            }
        }
    }

    // block reduce -> one fire-and-forget float atomic
#pragma unroll
    for (int off = 32; off; off >>= 1) local += __shfl_down(local, off);
    if (lane == 0) wsum[w] = local;
    __syncthreads();
    if (tid == 0) atomicAdd(out, wsum[0] + wsum[1] + wsum[2] + wsum[3]);
}

// ---------------- launch ----------------

extern "C" void kernel_launch(void* const* d_in, const int* in_sizes, int n_in,
                              void* d_out, int out_size, void* d_ws, size_t ws_size,
                              hipStream_t stream) {
    const float* x = (const float*)d_in[0];
    const int* labels = (const int*)d_in[1];
    float* out = (float*)d_out;

    char* p = (char*)d_ws;
    int* anchor = (int*)p;            p += C * 4;
    float* sq = (float*)p;            p += N * 4;
    float* ap = (float*)p;            p += N * 4;
    p = (char*)(((uintptr_t)p + 255) & ~(uintptr_t)255);
    float* T = (float*)p;             p += (size_t)C * N * 4;   // 16 MB
    _Float16* xh = (_Float16*)p;      // N*D*2 = 2 MB

    dim3 gf(C / BT, N / BT);
    k_front<<<gf, 256, 0, stream>>>(x, labels, xh, sq, anchor, T, ap, out);
    k_mega<<<C + NTRI, 256, 0, stream>>>(xh, labels, anchor, sq, ap, T, out);
}